// Round 1
// baseline (1418.418 us; speedup 1.0000x reference)
//
#include <hip/hip_runtime.h>
#include <hip/hip_bf16.h>
#include <math.h>

#define N 4
#define C 256
#define H 128
#define W 128
#define CO 288        // GROUP * K * K = 32 * 9
#define OH 126
#define OW 126
#define GROUP 32
#define CPG 8
#define EPS 1e-5f

#define HW (OH*OW)          // 15876
#define XSLICE (H*W)        // 16384
#define XNSTRIDE (C*H*W)    // 4194304
#define SNSTRIDE (CO*HW)    // 4572288
#define LONSTRIDE (C*HW)    // 4064256
#define WSTRIDE (CO*256)    // 73728 u16 per shift s

typedef unsigned short u16;
typedef __attribute__((ext_vector_type(8))) short short8;
typedef __attribute__((ext_vector_type(4))) float float4v;

__device__ inline u16 f2bf(float v) {
    __hip_bfloat16 b = __float2bfloat16(v);
    return __builtin_bit_cast(u16, b);
}
__device__ inline float bf2f(u16 u) {
    __hip_bfloat16 b = __builtin_bit_cast(__hip_bfloat16, u);
    return __bfloat162float(b);
}

// ---------------- Prep: split x into bf16 hi/lo, transpose to NHWC ----------------
// xh/xl layout: [n][h][w][ci] (ci contiguous)
__global__ __launch_bounds__(256) void split_x_kernel(const float* __restrict__ x,
                                                      u16* __restrict__ xh,
                                                      u16* __restrict__ xl) {
    const int ci = threadIdx.x;          // 0..255
    const int w0 = blockIdx.x * 8;       // 16 groups
    const int h  = blockIdx.y;
    const int n  = blockIdx.z;
    const float* src = x + ((size_t)(n*C + ci)*H + h)*W + w0;
    float4 v0 = *(const float4*)src;
    float4 v1 = *(const float4*)(src + 4);
    float vals[8] = {v0.x, v0.y, v0.z, v0.w, v1.x, v1.y, v1.z, v1.w};
    size_t obase = ((size_t)(n*H + h)*W + w0)*C + ci;
    #pragma unroll
    for (int dw = 0; dw < 8; ++dw) {
        float v = vals[dw];
        u16 hb = f2bf(v);
        xh[obase + (size_t)dw*C] = hb;
        xl[obase + (size_t)dw*C] = f2bf(v - bf2f(hb));
    }
}

// ---------------- Prep: split w into bf16 hi/lo, layout [s][co][ci] ----------------
__global__ __launch_bounds__(256) void split_w_kernel(const float* __restrict__ wgt,
                                                      u16* __restrict__ whT,
                                                      u16* __restrict__ wlT) {
    const int i = blockIdx.x*256 + threadIdx.x;  // < 9*288*256 = 663552
    const int ci = i & 255;
    const int co = (i >> 8) % CO;
    const int s  = i / (CO*256);
    float v = wgt[(size_t)co*(C*9) + (size_t)ci*9 + s];
    u16 hb = f2bf(v);
    whT[i] = hb;
    wlT[i] = f2bf(v - bf2f(hb));
}

// ---------------- Conv 3x3 VALID via bf16 MFMA implicit GEMM ----------------
// Grid (2, OH, N), block 256 = 4 waves.
// Block: 64 output positions (half row) x all 288 co.
// Wave grid 2M x 2C: wave (wm,wc) computes 32 positions x 144 co
//   -> acc[2 mt][9 j] float4 = 72 VGPR, B-fragments reused across 2 M-tiles.
// LDS layouts use 128B "rows" with XOR slot swizzle: slot = (sp*4+q) ^ (col&7)
//   -> all ds_read_b128 / ds_write_b128 patterns are <=2-way (free).
// K-loop: 8 ci-chunks of 32 x 9 shifts x 3 hi/lo products; next-segment w (and
// next-ci0 x) prefetched into registers after the post-stage barrier so global
// latency hides under the MFMA phase.
__global__ __launch_bounds__(256, 2) void conv_mfma_kernel(const u16* __restrict__ xh,
                                                           const u16* __restrict__ xl,
                                                           const u16* __restrict__ whT,
                                                           const u16* __restrict__ wlT,
                                                           float* __restrict__ sigma) {
    // xs: (ky, col 0..71, sp, ci-quad) -> u16 index ((ky*72+col)*64 + slot*8)
    __shared__ __align__(16) u16 xs[3*72*64];    // 27648 B
    // wsh: (co, sp, ci-quad) -> u16 index (co*64 + slot*8)
    __shared__ __align__(16) u16 wsh[288*64];    // 36864 B  (total 64512 B -> 2 blocks/CU)

    const int tid  = threadIdx.x;
    const int wave = tid >> 6;
    const int lane = tid & 63;
    const int m16  = lane & 15;
    const int q    = lane >> 4;
    const int wm   = wave & 1;      // M half (32 positions each)
    const int wc   = wave >> 1;     // co half (144 each)
    const int ow0  = blockIdx.x * 64;
    const int oh   = blockIdx.y;
    const int n    = blockIdx.z;

    // ---- staging constants (all shifts/masks, no div/mod) ----
    // W: chunk c = tid + 256k (k 0..8): co = (tid>>3)+32k, spq = tid&7
    const int w_co0  = tid >> 3;          // 0..31
    const int w_spq  = tid & 7;
    const u16* w_src = ((w_spq >> 2) ? wlT : whT) + (size_t)w_co0*256 + (w_spq & 3)*8;
    u16* w_dst = wsh + w_co0*64 + ((w_spq ^ (w_co0 & 7)) << 3);

    // X main: chunk c = tid + 256k (k 0..5): quad = tid&3, col = (tid>>2)&63,
    //         sp = k&1, row = k>>1.  ow0+col <= 127 always valid.
    const int x_quad = tid & 3;
    const int x_col  = (tid >> 2) & 63;
    const size_t x_srcoff = ((size_t)(n*H + oh)*W + ow0 + x_col)*C + x_quad*8;
    // X tail (cols 64,65): tid<48: quad=tid&3, col=64+((tid>>2)&1), sp=(tid>>3)&1, row=tid>>4
    const int t_quad = tid & 3;
    const int t_col  = 64 + ((tid >> 2) & 1);
    const int t_sp   = (tid >> 3) & 1;
    const int t_row  = tid >> 4;
    const bool t_on  = (tid < 48) && (ow0 + t_col < W);
    const size_t t_srcoff = ((size_t)(n*H + oh + t_row)*W + ow0 + t_col)*C + t_quad*8;

    uint4 wreg[9];
    uint4 xreg[6];
    uint4 xtail;

    // initial prefetch (ci0 = 0, s = 0)
    #pragma unroll
    for (int k = 0; k < 9; ++k)
        wreg[k] = *(const uint4*)(w_src + (size_t)k*8192);
    #pragma unroll
    for (int k = 0; k < 6; ++k) {
        const u16* p = ((k & 1) ? xl : xh) + x_srcoff + (size_t)(k >> 1)*(W*C);
        xreg[k] = *(const uint4*)p;
    }
    if (t_on) xtail = *(const uint4*)((t_sp ? xl : xh) + t_srcoff);

    float4v acc[2][9];
    #pragma unroll
    for (int mt = 0; mt < 2; ++mt)
        #pragma unroll
        for (int j = 0; j < 9; ++j) acc[mt][j] = (float4v)(0.f);

    for (int ci0 = 0; ci0 < C; ci0 += 32) {
        for (int s = 0; s < 9; ++s) {
            const int ky = s / 3;           // wave-uniform SALU
            const int kx = s - 3*ky;

            __syncthreads();                // readers of xs/wsh done
            #pragma unroll
            for (int k = 0; k < 9; ++k)
                *(uint4*)(w_dst + k*2048) = wreg[k];
            if (s == 0) {
                #pragma unroll
                for (int k = 0; k < 6; ++k) {
                    const int sp = k & 1, row = k >> 1;
                    const int slot = (sp*4 + x_quad) ^ (x_col & 7);
                    *(uint4*)(xs + (row*72 + x_col)*64 + slot*8) = xreg[k];
                }
                if (t_on) {
                    const int slot = (t_sp*4 + t_quad) ^ (t_col & 7);
                    *(uint4*)(xs + (t_row*72 + t_col)*64 + slot*8) = xtail;
                }
            }
            __syncthreads();                // xs/wsh ready

            // prefetch next segment's w (and next ci0's x) -> hides under MFMAs
            int ns = s + 1, nci = ci0;
            if (ns == 9) { ns = 0; nci += 32; }
            if (nci < C) {
                const u16* wsn = w_src + (size_t)ns*WSTRIDE + nci;
                #pragma unroll
                for (int k = 0; k < 9; ++k)
                    wreg[k] = *(const uint4*)(wsn + (size_t)k*8192);
                if (s == 8) {
                    #pragma unroll
                    for (int k = 0; k < 6; ++k) {
                        const u16* p = ((k & 1) ? xl : xh) + x_srcoff
                                     + (size_t)(k >> 1)*(W*C) + nci;
                        xreg[k] = *(const uint4*)p;
                    }
                    if (t_on) xtail = *(const uint4*)((t_sp ? xl : xh) + t_srcoff + nci);
                }
            }

            // ---- compute: 22 ds_read_b128, 54 MFMA per wave ----
            short8 ah[2], al[2];
            #pragma unroll
            for (int mt = 0; mt < 2; ++mt) {
                const int col = wm*32 + mt*16 + m16 + kx;
                const u16* xb = xs + (ky*72 + col)*64;
                ah[mt] = *(const short8*)(xb + ((q ^ (col & 7)) << 3));
                al[mt] = *(const short8*)(xb + (((4 + q) ^ (col & 7)) << 3));
            }
            const u16* wb = wsh + (wc*144 + m16)*64;
            const int bs0 = (q ^ (m16 & 7)) << 3;
            const int bs1 = ((4 + q) ^ (m16 & 7)) << 3;
            #pragma unroll
            for (int j = 0; j < 9; ++j) {
                short8 bh = *(const short8*)(wb + j*1024 + bs0);
                short8 bl = *(const short8*)(wb + j*1024 + bs1);
                #pragma unroll
                for (int mt = 0; mt < 2; ++mt) {
                    acc[mt][j] = __builtin_amdgcn_mfma_f32_16x16x32_bf16(ah[mt], bh, acc[mt][j], 0, 0, 0);
                    acc[mt][j] = __builtin_amdgcn_mfma_f32_16x16x32_bf16(al[mt], bh, acc[mt][j], 0, 0, 0);
                    acc[mt][j] = __builtin_amdgcn_mfma_f32_16x16x32_bf16(ah[mt], bl, acc[mt][j], 0, 0, 0);
                }
            }
        }
    }

    // store: D[row=q*4+r][col=m16]; pos = wm*32+mt*16+q*4+r, co = wc*144+j*16+m16
    #pragma unroll
    for (int mt = 0; mt < 2; ++mt) {
        const int posb = wm*32 + mt*16 + q*4;
        #pragma unroll
        for (int j = 0; j < 9; ++j) {
            const int co = wc*144 + j*16 + m16;
            float* dst = sigma + (size_t)n*SNSTRIDE + (size_t)co*HW + oh*OW;
            #pragma unroll
            for (int r = 0; r < 4; ++r) {
                const int ow = ow0 + posb + r;
                if (ow < OW) dst[ow] = acc[mt][j][r];
            }
        }
    }
}

// ---------------- Per-channel mean/var over (N, OH, OW) ----------------
__global__ __launch_bounds__(1024) void stats_kernel(const float* __restrict__ sigma,
                                                     const float* __restrict__ gamma,
                                                     const float* __restrict__ beta,
                                                     float* __restrict__ coef) {
    const int c = blockIdx.x;
    float sum = 0.f, sq = 0.f;
    for (int n = 0; n < N; ++n) {
        const float* sp = sigma + (size_t)n*SNSTRIDE + (size_t)c*HW;
        for (int i = threadIdx.x; i < HW; i += 1024) {
            float v = sp[i];
            sum += v; sq += v * v;
        }
    }
    for (int off = 32; off > 0; off >>= 1) {
        sum += __shfl_down(sum, off, 64);
        sq  += __shfl_down(sq,  off, 64);
    }
    __shared__ float ls[16], lq[16];
    const int wid = threadIdx.x >> 6, lane = threadIdx.x & 63;
    if (lane == 0) { ls[wid] = sum; lq[wid] = sq; }
    __syncthreads();
    if (threadIdx.x == 0) {
        float S = 0.f, Q = 0.f;
        #pragma unroll
        for (int i = 0; i < 16; ++i) { S += ls[i]; Q += lq[i]; }
        const float cnt = (float)(N * HW);
        float mean = S / cnt;
        float var  = Q / cnt - mean * mean;
        float a = gamma[c] * rsqrtf(var + EPS);
        coef[c]      = a;
        coef[CO + c] = beta[c] - mean * a;
    }
}

// ---------------- Fused normalize + softmax(288) + grouped dynamic 3x3 ----------------
__global__ __launch_bounds__(256) void fuse_kernel(const float* __restrict__ x,
                                                   const float* __restrict__ sigma,
                                                   const float* __restrict__ coef,
                                                   float* __restrict__ outlo) {
    __shared__ float a[CO], b[CO];
    for (int i = threadIdx.x; i < CO; i += 256) {
        a[i] = coef[i];
        b[i] = coef[CO + i];
    }
    __syncthreads();

    const int gpos = blockIdx.x * 256 + threadIdx.x;
    if (gpos >= N * HW) return;
    const int n  = gpos / HW;
    const int hw = gpos - n * HW;
    const int oh = hw / OW;
    const int ow = hw - oh * OW;

    const float* sp = sigma + (size_t)n * SNSTRIDE + hw;

    float mx = -1e30f;
    for (int ch = 0; ch < CO; ++ch) {
        float s = sp[(size_t)ch * HW] * a[ch] + b[ch];
        mx = fmaxf(mx, s);
    }
    float sum = 0.f;
    for (int ch = 0; ch < CO; ++ch) {
        float s = sp[(size_t)ch * HW] * a[ch] + b[ch];
        sum += __expf(s - mx);
    }
    const float inv = 1.f / sum;

    const float* xb = x + (size_t)n * XNSTRIDE + oh * W + ow;
    float* ob = outlo + (size_t)n * LONSTRIDE + hw;

    for (int g = 0; g < GROUP; ++g) {
        float acc[CPG];
        #pragma unroll
        for (int c = 0; c < CPG; ++c) acc[c] = 0.f;
        #pragma unroll
        for (int p = 0; p < 9; ++p) {
            const int ch = g * 9 + p;
            float s = sp[(size_t)ch * HW] * a[ch] + b[ch];
            float wv = __expf(s - mx) * inv;
            const float* xr = xb + (size_t)(g * CPG) * XSLICE + (p / 3) * W + (p % 3);
            #pragma unroll
            for (int c = 0; c < CPG; ++c)
                acc[c] += xr[(size_t)c * XSLICE] * wv;
        }
        #pragma unroll
        for (int c = 0; c < CPG; ++c)
            ob[(size_t)(g * CPG + c) * HW] = acc[c];
    }
}

// ---------------- Bilinear align-corners upsample 126 -> 128 ----------------
__global__ __launch_bounds__(256) void upsample_kernel(const float* __restrict__ lo,
                                                       float* __restrict__ out) {
    const int idx = blockIdx.x * 256 + threadIdx.x;
    const int xi = idx & (W - 1);
    const int yi = (idx >> 7) & (H - 1);
    const int nc = idx >> 14;

    const float scale = 125.0f / 127.0f;
    const float sy = yi * scale;
    const float sx = xi * scale;
    int y0 = (int)sy;
    int x0 = (int)sx;
    float wy = sy - (float)y0;
    float wx = sx - (float)x0;
    int y1 = min(y0 + 1, OH - 1);
    int x1 = min(x0 + 1, OW - 1);

    const float* p = lo + (size_t)nc * HW;
    float v00 = p[y0 * OW + x0], v01 = p[y0 * OW + x1];
    float v10 = p[y1 * OW + x0], v11 = p[y1 * OW + x1];
    float top = v00 * (1.f - wx) + v01 * wx;
    float bot = v10 * (1.f - wx) + v11 * wx;
    out[idx] = top * (1.f - wy) + bot * wy;
}

extern "C" void kernel_launch(void* const* d_in, const int* in_sizes, int n_in,
                              void* d_out, int out_size, void* d_ws, size_t ws_size,
                              hipStream_t stream) {
    const float* x      = (const float*)d_in[0];
    const float* conv_w = (const float*)d_in[1];
    const float* gamma  = (const float*)d_in[2];
    const float* beta   = (const float*)d_in[3];
    float* out = (float*)d_out;
    float* ws  = (float*)d_ws;

    // workspace (floats):
    //   sigma : [0, 18289152)
    //   coef  : [18289152, +1024)
    //   outlo : [18290176, +16257024)   -- ALIASED with xh/xl (prep+conv finish first)
    float* sigma = ws;
    float* coef  = ws + 18289152;
    float* outlo = ws + 18290176;
    u16* xhp = (u16*)(ws + 18290176);               // 16777216 u16 = 33.5 MB
    u16* xlp = xhp + (size_t)N*H*W*C;               // 16777216 u16
    u16* whT = xlp + (size_t)N*H*W*C;               // 663552 u16
    u16* wlT = whT + (size_t)9*CO*256;              // 663552 u16
    // total ws usage ~143 MB

    split_x_kernel<<<dim3(16, 128, 4), 256, 0, stream>>>(x, xhp, xlp);
    split_w_kernel<<<(9*CO*256)/256, 256, 0, stream>>>(conv_w, whT, wlT);

    conv_mfma_kernel<<<dim3(2, OH, N), 256, 0, stream>>>(xhp, xlp, whT, wlT, sigma);

    stats_kernel<<<CO, 1024, 0, stream>>>(sigma, gamma, beta, coef);

    fuse_kernel<<<(N * HW + 255) / 256, 256, 0, stream>>>(x, sigma, coef, outlo);

    upsample_kernel<<<(N * C * H * W) / 256, 256, 0, stream>>>(outlo, out);
}

// Round 2
// 863.161 us; speedup vs baseline: 1.6433x; 1.6433x over previous
//
#include <hip/hip_runtime.h>
#include <hip/hip_bf16.h>
#include <math.h>

#define N 4
#define C 256
#define H 128
#define W 128
#define CO 288        // GROUP * K * K = 32 * 9
#define OH 126
#define OW 126
#define GROUP 32
#define CPG 8
#define EPS 1e-5f

#define HW (OH*OW)          // 15876
#define XSLICE (H*W)        // 16384
#define XNSTRIDE (C*H*W)    // 4194304
#define SNSTRIDE (CO*HW)    // 4572288
#define LONSTRIDE (C*HW)    // 4064256
#define WSTRIDE (CO*256)    // 73728 u16 per shift s
#define WTOT (9*CO*256)     // 663552 u16 per table (wlT = whT + WTOT)
#define XTOT (N*H*W*C)      // 16777216 u16 per table (xl = xh + XTOT)

typedef unsigned short u16;
typedef __attribute__((ext_vector_type(8))) short short8;
typedef __attribute__((ext_vector_type(4))) float float4v;

__device__ inline u16 f2bf(float v) {
    __hip_bfloat16 b = __float2bfloat16(v);
    return __builtin_bit_cast(u16, b);
}
__device__ inline float bf2f(u16 u) {
    __hip_bfloat16 b = __builtin_bit_cast(__hip_bfloat16, u);
    return __bfloat162float(b);
}

// ---------------- Prep: split x into bf16 hi/lo, transpose to NHWC ----------------
// xh/xl layout: [n][h][w][ci] (ci contiguous); xl MUST be at xh + XTOT.
__global__ __launch_bounds__(256) void split_x_kernel(const float* __restrict__ x,
                                                      u16* __restrict__ xh,
                                                      u16* __restrict__ xl) {
    const int ci = threadIdx.x;          // 0..255
    const int w0 = blockIdx.x * 8;       // 16 groups
    const int h  = blockIdx.y;
    const int n  = blockIdx.z;
    const float* src = x + ((size_t)(n*C + ci)*H + h)*W + w0;
    float4 v0 = *(const float4*)src;
    float4 v1 = *(const float4*)(src + 4);
    float vals[8] = {v0.x, v0.y, v0.z, v0.w, v1.x, v1.y, v1.z, v1.w};
    size_t obase = ((size_t)(n*H + h)*W + w0)*C + ci;
    #pragma unroll
    for (int dw = 0; dw < 8; ++dw) {
        float v = vals[dw];
        u16 hb = f2bf(v);
        xh[obase + (size_t)dw*C] = hb;
        xl[obase + (size_t)dw*C] = f2bf(v - bf2f(hb));
    }
}

// ---------------- Prep: split w into bf16 hi/lo, layout [s][co][ci] ----------------
__global__ __launch_bounds__(256) void split_w_kernel(const float* __restrict__ wgt,
                                                      u16* __restrict__ whT,
                                                      u16* __restrict__ wlT) {
    const int i = blockIdx.x*256 + threadIdx.x;  // < 9*288*256 = 663552
    const int ci = i & 255;
    const int co = (i >> 8) % CO;
    const int s  = i / (CO*256);
    float v = wgt[(size_t)co*(C*9) + (size_t)ci*9 + s];
    u16 hb = f2bf(v);
    whT[i] = hb;
    wlT[i] = f2bf(v - bf2f(hb));
}

// ---------------- Conv 3x3 VALID via bf16 MFMA implicit GEMM ----------------
// Grid (2, OH, N), block 256 = 4 waves.
// Block: 64 output positions (half row) x all 288 co.
// Wave grid 2M x 2C: wave (wm,wc) = 32 positions x 144 co, acc[2][9] float4.
//
// LDS layouts put the (split,ci-quad) slot OUTERMOST so that:
//   - MFMA fragment reads: each 16-lane group reads 256 contiguous bytes
//     (uniform bank coverage, no conflicts, no swizzle needed)
//   - staging is linear in chunk index -> global_load_lds (wave-uniform LDS
//     dest + lane*16) works directly. No VGPR staging, nothing to spill.
// Per-lane global source offsets are loop-invariant, computed once at init.
__global__ __launch_bounds__(256) void conv_mfma_kernel(const u16* __restrict__ xh,
                                                        const u16* __restrict__ whT,
                                                        float* __restrict__ sigma) {
    // xs chunk c = spq*216 + row*72 + col  (spq = sp*4+q), 8 u16 per chunk
    __shared__ __align__(16) u16 xs[8*3*72*8];    // 27648 B
    // wsh chunk c = spq*288 + co, 8 u16 per chunk
    __shared__ __align__(16) u16 wsh[8*288*8];    // 36864 B  (total 64512 -> 2 blk/CU)

    const int tid  = threadIdx.x;
    const int wave = tid >> 6;
    const int lane = tid & 63;
    const int m16  = lane & 15;
    const int q    = lane >> 4;
    const int wm   = wave & 1;      // M half (32 positions each)
    const int wc   = wave >> 1;     // co half (144 each)
    const int ow0  = blockIdx.x * 64;
    const int oh   = blockIdx.y;
    const int n    = blockIdx.z;

    // ---- per-lane staging source offsets (init once; read-only thereafter) ----
    // w: 2304 chunks, wave v issues i=0..8 covering chunks (v*9+i)*64 + lane
    int woff[9];
    #pragma unroll
    for (int i = 0; i < 9; ++i) {
        const int c   = (wave*9 + i)*64 + lane;
        const int spq = c / 288;
        const int co  = c - spq*288;
        woff[i] = (spq >> 2)*WTOT + co*256 + (spq & 3)*8;
    }
    // x: 1728 chunks, issues idx=0..26; wave v takes idx = 4t+v (t<6 or v<3)
    int xoff[7];
    #pragma unroll
    for (int t = 0; t < 7; ++t) {
        int c = (4*t + wave)*64 + lane;
        if (c > 1727) c = 1727;                       // unused (guarded at issue)
        const int spq = c / 216;
        const int rem = c - spq*216;
        const int row = rem / 72;
        const int col = rem - row*72;
        int wcl = ow0 + col; if (wcl > W-1) wcl = W-1;  // clamp: feeds discarded outputs only
        xoff[t] = (spq >> 2)*XTOT + ((n*H + oh + row)*W + wcl)*C + (spq & 3)*8;
    }

    // ---- fragment read offsets (u16 elements) ----
    const int aoffh = (q*216 + wm*32 + m16)*8;     // + (ky*72+kx)*8 + mt*128
    const int aoffl = aoffh + 4*216*8;
    const int boffh = (q*288 + wc*144 + m16)*8;    // + j*128
    const int boffl = boffh + 4*288*8;

    float4v acc[2][9];
    #pragma unroll
    for (int mt = 0; mt < 2; ++mt)
        #pragma unroll
        for (int j = 0; j < 9; ++j) acc[mt][j] = (float4v)(0.f);

    for (int ci0 = 0; ci0 < C; ci0 += 32) {
        #pragma unroll
        for (int ky = 0; ky < 3; ++ky)
        #pragma unroll
        for (int kx = 0; kx < 3; ++kx) {
            const int s = ky*3 + kx;

            __syncthreads();               // all readers of xs/wsh done
            // stage w[s] chunk-linear via global_load_lds (9 issues/wave)
            #pragma unroll
            for (int i = 0; i < 9; ++i)
                __builtin_amdgcn_global_load_lds(
                    (const uint*)(whT + woff[i] + s*WSTRIDE + ci0),
                    (uint*)(wsh + (wave*9 + i)*512), 16, 0, 0);
            if (s == 0) {                  // stage x tile once per ci0
                #pragma unroll
                for (int t = 0; t < 7; ++t)
                    if (t < 6 || wave < 3)
                        __builtin_amdgcn_global_load_lds(
                            (const uint*)(xh + xoff[t] + ci0),
                            (uint*)(xs + (4*t + wave)*512), 16, 0, 0);
            }
            __syncthreads();               // vmcnt drained before barrier -> data visible

            // ---- compute: 22 ds_read_b128 + 54 MFMA per wave ----
            const int ab = aoffh + (ky*72 + kx)*8;
            const int al_b = aoffl + (ky*72 + kx)*8;
            short8 ah0 = *(const short8*)&xs[ab];
            short8 ah1 = *(const short8*)&xs[ab + 128];
            short8 al0 = *(const short8*)&xs[al_b];
            short8 al1 = *(const short8*)&xs[al_b + 128];
            #pragma unroll
            for (int j = 0; j < 9; ++j) {
                short8 bh = *(const short8*)&wsh[boffh + j*128];
                short8 bl = *(const short8*)&wsh[boffl + j*128];
                acc[0][j] = __builtin_amdgcn_mfma_f32_16x16x32_bf16(ah0, bh, acc[0][j], 0, 0, 0);
                acc[1][j] = __builtin_amdgcn_mfma_f32_16x16x32_bf16(ah1, bh, acc[1][j], 0, 0, 0);
                acc[0][j] = __builtin_amdgcn_mfma_f32_16x16x32_bf16(al0, bh, acc[0][j], 0, 0, 0);
                acc[1][j] = __builtin_amdgcn_mfma_f32_16x16x32_bf16(al1, bh, acc[1][j], 0, 0, 0);
                acc[0][j] = __builtin_amdgcn_mfma_f32_16x16x32_bf16(ah0, bl, acc[0][j], 0, 0, 0);
                acc[1][j] = __builtin_amdgcn_mfma_f32_16x16x32_bf16(ah1, bl, acc[1][j], 0, 0, 0);
            }
        }
    }

    // store: D[row=q*4+r][col=m16]; pos = wm*32+mt*16+q*4+r, co = wc*144+j*16+m16
    #pragma unroll
    for (int mt = 0; mt < 2; ++mt) {
        const int posb = wm*32 + mt*16 + q*4;
        #pragma unroll
        for (int j = 0; j < 9; ++j) {
            const int co = wc*144 + j*16 + m16;
            float* dst = sigma + (size_t)n*SNSTRIDE + (size_t)co*HW + oh*OW;
            #pragma unroll
            for (int r = 0; r < 4; ++r) {
                const int ow = ow0 + posb + r;
                if (ow < OW) dst[ow] = acc[mt][j][r];
            }
        }
    }
}

// ---------------- Per-channel mean/var over (N, OH, OW) ----------------
__global__ __launch_bounds__(1024) void stats_kernel(const float* __restrict__ sigma,
                                                     const float* __restrict__ gamma,
                                                     const float* __restrict__ beta,
                                                     float* __restrict__ coef) {
    const int c = blockIdx.x;
    float sum = 0.f, sq = 0.f;
    for (int n = 0; n < N; ++n) {
        const float* sp = sigma + (size_t)n*SNSTRIDE + (size_t)c*HW;
        for (int i = threadIdx.x; i < HW; i += 1024) {
            float v = sp[i];
            sum += v; sq += v * v;
        }
    }
    for (int off = 32; off > 0; off >>= 1) {
        sum += __shfl_down(sum, off, 64);
        sq  += __shfl_down(sq,  off, 64);
    }
    __shared__ float ls[16], lq[16];
    const int wid = threadIdx.x >> 6, lane = threadIdx.x & 63;
    if (lane == 0) { ls[wid] = sum; lq[wid] = sq; }
    __syncthreads();
    if (threadIdx.x == 0) {
        float S = 0.f, Q = 0.f;
        #pragma unroll
        for (int i = 0; i < 16; ++i) { S += ls[i]; Q += lq[i]; }
        const float cnt = (float)(N * HW);
        float mean = S / cnt;
        float var  = Q / cnt - mean * mean;
        float a = gamma[c] * rsqrtf(var + EPS);
        coef[c]      = a;
        coef[CO + c] = beta[c] - mean * a;
    }
}

// ---------------- Fused normalize + softmax(288) + grouped dynamic 3x3 ----------------
__global__ __launch_bounds__(256) void fuse_kernel(const float* __restrict__ x,
                                                   const float* __restrict__ sigma,
                                                   const float* __restrict__ coef,
                                                   float* __restrict__ outlo) {
    __shared__ float a[CO], b[CO];
    for (int i = threadIdx.x; i < CO; i += 256) {
        a[i] = coef[i];
        b[i] = coef[CO + i];
    }
    __syncthreads();

    const int gpos = blockIdx.x * 256 + threadIdx.x;
    if (gpos >= N * HW) return;
    const int n  = gpos / HW;
    const int hw = gpos - n * HW;
    const int oh = hw / OW;
    const int ow = hw - oh * OW;

    const float* sp = sigma + (size_t)n * SNSTRIDE + hw;

    float mx = -1e30f;
    for (int ch = 0; ch < CO; ++ch) {
        float s = sp[(size_t)ch * HW] * a[ch] + b[ch];
        mx = fmaxf(mx, s);
    }
    float sum = 0.f;
    for (int ch = 0; ch < CO; ++ch) {
        float s = sp[(size_t)ch * HW] * a[ch] + b[ch];
        sum += __expf(s - mx);
    }
    const float inv = 1.f / sum;

    const float* xb = x + (size_t)n * XNSTRIDE + oh * W + ow;
    float* ob = outlo + (size_t)n * LONSTRIDE + hw;

    for (int g = 0; g < GROUP; ++g) {
        float acc[CPG];
        #pragma unroll
        for (int c = 0; c < CPG; ++c) acc[c] = 0.f;
        #pragma unroll
        for (int p = 0; p < 9; ++p) {
            const int ch = g * 9 + p;
            float s = sp[(size_t)ch * HW] * a[ch] + b[ch];
            float wv = __expf(s - mx) * inv;
            const float* xr = xb + (size_t)(g * CPG) * XSLICE + (p / 3) * W + (p % 3);
            #pragma unroll
            for (int c = 0; c < CPG; ++c)
                acc[c] += xr[(size_t)c * XSLICE] * wv;
        }
        #pragma unroll
        for (int c = 0; c < CPG; ++c)
            ob[(size_t)(g * CPG + c) * HW] = acc[c];
    }
}

// ---------------- Bilinear align-corners upsample 126 -> 128 ----------------
__global__ __launch_bounds__(256) void upsample_kernel(const float* __restrict__ lo,
                                                       float* __restrict__ out) {
    const int idx = blockIdx.x * 256 + threadIdx.x;
    const int xi = idx & (W - 1);
    const int yi = (idx >> 7) & (H - 1);
    const int nc = idx >> 14;

    const float scale = 125.0f / 127.0f;
    const float sy = yi * scale;
    const float sx = xi * scale;
    int y0 = (int)sy;
    int x0 = (int)sx;
    float wy = sy - (float)y0;
    float wx = sx - (float)x0;
    int y1 = min(y0 + 1, OH - 1);
    int x1 = min(x0 + 1, OW - 1);

    const float* p = lo + (size_t)nc * HW;
    float v00 = p[y0 * OW + x0], v01 = p[y0 * OW + x1];
    float v10 = p[y1 * OW + x0], v11 = p[y1 * OW + x1];
    float top = v00 * (1.f - wx) + v01 * wx;
    float bot = v10 * (1.f - wx) + v11 * wx;
    out[idx] = top * (1.f - wy) + bot * wy;
}

extern "C" void kernel_launch(void* const* d_in, const int* in_sizes, int n_in,
                              void* d_out, int out_size, void* d_ws, size_t ws_size,
                              hipStream_t stream) {
    const float* x      = (const float*)d_in[0];
    const float* conv_w = (const float*)d_in[1];
    const float* gamma  = (const float*)d_in[2];
    const float* beta   = (const float*)d_in[3];
    float* out = (float*)d_out;
    float* ws  = (float*)d_ws;

    // workspace (floats):
    //   sigma : [0, 18289152)
    //   coef  : [18289152, +1024)
    //   outlo : [18290176, +16257024)   -- ALIASED with xh/xl (prep+conv finish first)
    float* sigma = ws;
    float* coef  = ws + 18289152;
    float* outlo = ws + 18290176;
    u16* xhp = (u16*)(ws + 18290176);               // 16777216 u16 = 33.5 MB
    u16* xlp = xhp + (size_t)XTOT;                  // adjacent: xl = xh + XTOT
    u16* whT = xlp + (size_t)XTOT;                  // 663552 u16
    u16* wlT = whT + (size_t)WTOT;                  // adjacent: wl = wh + WTOT
    // total ws usage ~143 MB

    split_x_kernel<<<dim3(16, 128, 4), 256, 0, stream>>>(x, xhp, xlp);
    split_w_kernel<<<(9*CO*256)/256, 256, 0, stream>>>(conv_w, whT, wlT);

    conv_mfma_kernel<<<dim3(2, OH, N), 256, 0, stream>>>(xhp, whT, sigma);

    stats_kernel<<<CO, 1024, 0, stream>>>(sigma, gamma, beta, coef);

    fuse_kernel<<<(N * HW + 255) / 256, 256, 0, stream>>>(x, sigma, coef, outlo);

    upsample_kernel<<<(N * C * H * W) / 256, 256, 0, stream>>>(outlo, out);
}

// Round 3
// 784.094 us; speedup vs baseline: 1.8090x; 1.1008x over previous
//
#include <hip/hip_runtime.h>
#include <hip/hip_bf16.h>
#include <math.h>

#define N 4
#define C 256
#define H 128
#define W 128
#define CO 288        // GROUP * K * K = 32 * 9
#define OH 126
#define OW 126
#define GROUP 32
#define CPG 8
#define EPS 1e-5f

#define HW (OH*OW)          // 15876
#define XSLICE (H*W)        // 16384
#define XNSTRIDE (C*H*W)    // 4194304
#define SNSTRIDE (CO*HW)    // 4572288
#define LONSTRIDE (C*HW)    // 4064256
#define WSTRIDE (CO*256)    // 73728 u16 per shift s
#define WTOT (9*CO*256)     // 663552 u16 per table (wlT = whT + WTOT)
#define XTOT (N*H*W*C)      // 16777216 u16 per table (xl = xh + XTOT)

typedef unsigned short u16;
typedef __attribute__((ext_vector_type(8))) short short8;
typedef __attribute__((ext_vector_type(4))) float float4v;

__device__ inline u16 f2bf(float v) {
    __hip_bfloat16 b = __float2bfloat16(v);
    return __builtin_bit_cast(u16, b);
}
__device__ inline float bf2f(u16 u) {
    __hip_bfloat16 b = __builtin_bit_cast(__hip_bfloat16, u);
    return __bfloat162float(b);
}

// ---------------- Prep: split x into bf16 hi/lo, transpose to NHWC ----------------
// xh/xl layout: [n][h][w][ci] (ci contiguous); xl MUST be at xh + XTOT.
__global__ __launch_bounds__(256) void split_x_kernel(const float* __restrict__ x,
                                                      u16* __restrict__ xh,
                                                      u16* __restrict__ xl) {
    const int ci = threadIdx.x;          // 0..255
    const int w0 = blockIdx.x * 8;       // 16 groups
    const int h  = blockIdx.y;
    const int n  = blockIdx.z;
    const float* src = x + ((size_t)(n*C + ci)*H + h)*W + w0;
    float4 v0 = *(const float4*)src;
    float4 v1 = *(const float4*)(src + 4);
    float vals[8] = {v0.x, v0.y, v0.z, v0.w, v1.x, v1.y, v1.z, v1.w};
    size_t obase = ((size_t)(n*H + h)*W + w0)*C + ci;
    #pragma unroll
    for (int dw = 0; dw < 8; ++dw) {
        float v = vals[dw];
        u16 hb = f2bf(v);
        xh[obase + (size_t)dw*C] = hb;
        xl[obase + (size_t)dw*C] = f2bf(v - bf2f(hb));
    }
}

// ---------------- Prep: split w into bf16 hi/lo, layout [s][co][ci] ----------------
__global__ __launch_bounds__(256) void split_w_kernel(const float* __restrict__ wgt,
                                                      u16* __restrict__ whT,
                                                      u16* __restrict__ wlT) {
    const int i = blockIdx.x*256 + threadIdx.x;  // < 9*288*256 = 663552
    const int ci = i & 255;
    const int co = (i >> 8) % CO;
    const int s  = i / (CO*256);
    float v = wgt[(size_t)co*(C*9) + (size_t)ci*9 + s];
    u16 hb = f2bf(v);
    whT[i] = hb;
    wlT[i] = f2bf(v - bf2f(hb));
}

// ---------------- Conv 3x3 VALID via bf16 MFMA implicit GEMM ----------------
// Grid (2, OH, N), block 256 = 4 waves; wave (wm,wc) = 32 pos x 144 co.
//
// Pipelined K-loop: 8 ci-chunks x 9 shifts x 2 sub-units {bh: 36 MFMA, bl: 18 MFMA}
// = 144 units. wsh is double-buffered (2 x 18432 B, one split each); each unit
// issues the NEXT unit's global_load_lds before its own compute, so the
// vmcnt(0) drain at the unit-ending __syncthreads covers loads that already
// had a full MFMA phase to land (T3 issue-early pattern). xs single-buffered,
// restaged with a dedicated drain barrier once per ci0 (7x per block).
// A-fragments are read once per shift and held in VGPRs across the intra-s barrier.
__global__ __launch_bounds__(256) void conv_mfma_kernel(const u16* __restrict__ xh,
                                                        const u16* __restrict__ whT,
                                                        float* __restrict__ sigma) {
    // xs chunk c = spq*216 + row*72 + col (spq = sp*4+q), 8 u16 per chunk
    __shared__ __align__(16) u16 xs[8*3*72*8];       // 27648 B
    // wsh: 2 buffers, each chunk c = q*288 + co, 8 u16 per chunk (one split/buffer)
    __shared__ __align__(16) u16 wsh[2*4*288*8];     // 36864 B (total 64512 -> 2 blk/CU)

    const int tid  = threadIdx.x;
    const int wave = tid >> 6;
    const int lane = tid & 63;
    const int m16  = lane & 15;
    const int q    = lane >> 4;
    const int wm   = wave & 1;      // M half (32 positions each)
    const int wc   = wave >> 1;     // co half (144 each)
    const int ow0  = blockIdx.x * 64;
    const int oh   = blockIdx.y;
    const int n    = blockIdx.z;

    // ---- w staging: 1152 chunks [q][co]; wave distribution 5/5/4/4 issues ----
    const int w_nw   = (wave < 2) ? 5 : 4;
    const int w_base = (wave < 2) ? wave*320 : 640 + (wave-2)*256;
    int wsrc[5];
    #pragma unroll
    for (int i = 0; i < 5; ++i) {
        int c = w_base + i*64 + lane;
        if (c > 1151) c = 1151;                      // only reached by unused issues
        const int cq  = c / 288;
        const int cco = c - cq*288;
        wsrc[i] = cco*256 + cq*8;                    // + split*WTOT + s*WSTRIDE + ci0
    }

    // ---- x staging: 1728 chunks; issues idx = 4t+wave, t<7, guard ----
    int xoff[7];
    #pragma unroll
    for (int t = 0; t < 7; ++t) {
        int c = (4*t + wave)*64 + lane;
        if (c > 1727) c = 1727;                      // unused (guarded at issue)
        const int spq = c / 216;
        const int rem = c - spq*216;
        const int row = rem / 72;
        const int col = rem - row*72;
        int wcl = ow0 + col; if (wcl > W-1) wcl = W-1;  // clamp feeds discarded outputs
        xoff[t] = (spq >> 2)*XTOT + ((n*H + oh + row)*W + wcl)*C + (spq & 3)*8;
    }

    // ---- fragment read offsets (u16 units) ----
    const int aoffh = (q*216 + wm*32 + m16)*8;       // + (ky*72+kx)*8 + mt*128
    const int aoffl = aoffh + 4*216*8;
    const int boff  = (q*288 + wc*144 + m16)*8;      // + buf*9216 + j*128

    float4v acc[2][9];
    #pragma unroll
    for (int mt = 0; mt < 2; ++mt)
        #pragma unroll
        for (int j = 0; j < 9; ++j) acc[mt][j] = (float4v)(0.f);

    // ---- prologue: stage xs(ci0=0) and w unit0 (s=0, hi) into buf 0 ----
    #pragma unroll
    for (int t = 0; t < 7; ++t)
        if (t < 6 || wave < 3)
            __builtin_amdgcn_global_load_lds((const uint*)(xh + xoff[t]),
                                             (uint*)(xs + (4*t + wave)*512), 16, 0, 0);
    #pragma unroll
    for (int i = 0; i < 5; ++i)
        if (i < w_nw)
            __builtin_amdgcn_global_load_lds((const uint*)(whT + wsrc[i]),
                                             (uint*)(wsh + (w_base + i*64)*8), 16, 0, 0);
    __syncthreads();

    int buf = 0;
    for (int ci0 = 0; ci0 < C; ci0 += 32) {
        #pragma unroll
        for (int ky = 0; ky < 3; ++ky)
        #pragma unroll
        for (int kx = 0; kx < 3; ++kx) {
            const int s = ky*3 + kx;

            // ======== unit A (bh): compute on buf, issue bl(s) into buf^1 ========
            {
                const int soff = WTOT + s*WSTRIDE + ci0;     // lo split, same s
                #pragma unroll
                for (int i = 0; i < 5; ++i)
                    if (i < w_nw)
                        __builtin_amdgcn_global_load_lds(
                            (const uint*)(whT + soff + wsrc[i]),
                            (uint*)(wsh + ((buf^1)*1152 + w_base + i*64)*8), 16, 0, 0);
            }
            const int ao  = aoffh + (ky*72 + kx)*8;
            const int alo = aoffl + (ky*72 + kx)*8;
            short8 ah0 = *(const short8*)&xs[ao];
            short8 ah1 = *(const short8*)&xs[ao + 128];
            short8 al0 = *(const short8*)&xs[alo];
            short8 al1 = *(const short8*)&xs[alo + 128];
            {
                const u16* wb = wsh + buf*9216 + boff;
                #pragma unroll
                for (int j = 0; j < 9; ++j) {
                    short8 bh = *(const short8*)&wb[j*128];
                    acc[0][j] = __builtin_amdgcn_mfma_f32_16x16x32_bf16(ah0, bh, acc[0][j], 0, 0, 0);
                    acc[1][j] = __builtin_amdgcn_mfma_f32_16x16x32_bf16(ah1, bh, acc[1][j], 0, 0, 0);
                    acc[0][j] = __builtin_amdgcn_mfma_f32_16x16x32_bf16(al0, bh, acc[0][j], 0, 0, 0);
                    acc[1][j] = __builtin_amdgcn_mfma_f32_16x16x32_bf16(al1, bh, acc[1][j], 0, 0, 0);
                }
            }
            __syncthreads();     // drains bl(s) loads; bh buffer readers done
            buf ^= 1;

            // ======== unit B (bl): compute on buf, issue next unit's hi into buf^1 ====
            if (!(ci0 == C-32 && s == 8)) {
                int ns = s + 1, nci = ci0;
                if (ns == 9) { ns = 0; nci += 32; }
                const int soff = ns*WSTRIDE + nci;           // hi split of next unit
                #pragma unroll
                for (int i = 0; i < 5; ++i)
                    if (i < w_nw)
                        __builtin_amdgcn_global_load_lds(
                            (const uint*)(whT + soff + wsrc[i]),
                            (uint*)(wsh + ((buf^1)*1152 + w_base + i*64)*8), 16, 0, 0);
            }
            {
                const u16* wb = wsh + buf*9216 + boff;
                #pragma unroll
                for (int j = 0; j < 9; ++j) {
                    short8 bl = *(const short8*)&wb[j*128];
                    acc[0][j] = __builtin_amdgcn_mfma_f32_16x16x32_bf16(ah0, bl, acc[0][j], 0, 0, 0);
                    acc[1][j] = __builtin_amdgcn_mfma_f32_16x16x32_bf16(ah1, bl, acc[1][j], 0, 0, 0);
                }
            }
            __syncthreads();     // drains next unit's hi loads; bl buffer readers done
            buf ^= 1;
        }

        // ---- ci0 boundary: restage xs (its readers finished at the last barrier) ----
        if (ci0 != C-32) {
            const int nci = ci0 + 32;
            #pragma unroll
            for (int t = 0; t < 7; ++t)
                if (t < 6 || wave < 3)
                    __builtin_amdgcn_global_load_lds((const uint*)(xh + xoff[t] + nci),
                                                     (uint*)(xs + (4*t + wave)*512), 16, 0, 0);
            __syncthreads();
        }
    }

    // store: D[row=q*4+r][col=m16]; pos = wm*32+mt*16+q*4+r, co = wc*144+j*16+m16
    #pragma unroll
    for (int mt = 0; mt < 2; ++mt) {
        const int posb = wm*32 + mt*16 + q*4;
        #pragma unroll
        for (int j = 0; j < 9; ++j) {
            const int co = wc*144 + j*16 + m16;
            float* dst = sigma + (size_t)n*SNSTRIDE + (size_t)co*HW + oh*OW;
            #pragma unroll
            for (int r = 0; r < 4; ++r) {
                const int ow = ow0 + posb + r;
                if (ow < OW) dst[ow] = acc[mt][j][r];
            }
        }
    }
}

// ---------------- Per-channel mean/var over (N, OH, OW) ----------------
__global__ __launch_bounds__(1024) void stats_kernel(const float* __restrict__ sigma,
                                                     const float* __restrict__ gamma,
                                                     const float* __restrict__ beta,
                                                     float* __restrict__ coef) {
    const int c = blockIdx.x;
    float sum = 0.f, sq = 0.f;
    for (int n = 0; n < N; ++n) {
        const float* sp = sigma + (size_t)n*SNSTRIDE + (size_t)c*HW;
        for (int i = threadIdx.x; i < HW; i += 1024) {
            float v = sp[i];
            sum += v; sq += v * v;
        }
    }
    for (int off = 32; off > 0; off >>= 1) {
        sum += __shfl_down(sum, off, 64);
        sq  += __shfl_down(sq,  off, 64);
    }
    __shared__ float ls[16], lq[16];
    const int wid = threadIdx.x >> 6, lane = threadIdx.x & 63;
    if (lane == 0) { ls[wid] = sum; lq[wid] = sq; }
    __syncthreads();
    if (threadIdx.x == 0) {
        float S = 0.f, Q = 0.f;
        #pragma unroll
        for (int i = 0; i < 16; ++i) { S += ls[i]; Q += lq[i]; }
        const float cnt = (float)(N * HW);
        float mean = S / cnt;
        float var  = Q / cnt - mean * mean;
        float a = gamma[c] * rsqrtf(var + EPS);
        coef[c]      = a;
        coef[CO + c] = beta[c] - mean * a;
    }
}

// ---------------- Fused normalize + softmax(288) + grouped dynamic 3x3 ----------------
__global__ __launch_bounds__(256) void fuse_kernel(const float* __restrict__ x,
                                                   const float* __restrict__ sigma,
                                                   const float* __restrict__ coef,
                                                   float* __restrict__ outlo) {
    __shared__ float a[CO], b[CO];
    for (int i = threadIdx.x; i < CO; i += 256) {
        a[i] = coef[i];
        b[i] = coef[CO + i];
    }
    __syncthreads();

    const int gpos = blockIdx.x * 256 + threadIdx.x;
    if (gpos >= N * HW) return;
    const int n  = gpos / HW;
    const int hw = gpos - n * HW;
    const int oh = hw / OW;
    const int ow = hw - oh * OW;

    const float* sp = sigma + (size_t)n * SNSTRIDE + hw;

    float mx = -1e30f;
    for (int ch = 0; ch < CO; ++ch) {
        float s = sp[(size_t)ch * HW] * a[ch] + b[ch];
        mx = fmaxf(mx, s);
    }
    float sum = 0.f;
    for (int ch = 0; ch < CO; ++ch) {
        float s = sp[(size_t)ch * HW] * a[ch] + b[ch];
        sum += __expf(s - mx);
    }
    const float inv = 1.f / sum;

    const float* xb = x + (size_t)n * XNSTRIDE + oh * W + ow;
    float* ob = outlo + (size_t)n * LONSTRIDE + hw;

    for (int g = 0; g < GROUP; ++g) {
        float acc[CPG];
        #pragma unroll
        for (int c = 0; c < CPG; ++c) acc[c] = 0.f;
        #pragma unroll
        for (int p = 0; p < 9; ++p) {
            const int ch = g * 9 + p;
            float s = sp[(size_t)ch * HW] * a[ch] + b[ch];
            float wv = __expf(s - mx) * inv;
            const float* xr = xb + (size_t)(g * CPG) * XSLICE + (p / 3) * W + (p % 3);
            #pragma unroll
            for (int c = 0; c < CPG; ++c)
                acc[c] += xr[(size_t)c * XSLICE] * wv;
        }
        #pragma unroll
        for (int c = 0; c < CPG; ++c)
            ob[(size_t)(g * CPG + c) * HW] = acc[c];
    }
}

// ---------------- Bilinear align-corners upsample 126 -> 128 ----------------
__global__ __launch_bounds__(256) void upsample_kernel(const float* __restrict__ lo,
                                                       float* __restrict__ out) {
    const int idx = blockIdx.x * 256 + threadIdx.x;
    const int xi = idx & (W - 1);
    const int yi = (idx >> 7) & (H - 1);
    const int nc = idx >> 14;

    const float scale = 125.0f / 127.0f;
    const float sy = yi * scale;
    const float sx = xi * scale;
    int y0 = (int)sy;
    int x0 = (int)sx;
    float wy = sy - (float)y0;
    float wx = sx - (float)x0;
    int y1 = min(y0 + 1, OH - 1);
    int x1 = min(x0 + 1, OW - 1);

    const float* p = lo + (size_t)nc * HW;
    float v00 = p[y0 * OW + x0], v01 = p[y0 * OW + x1];
    float v10 = p[y1 * OW + x0], v11 = p[y1 * OW + x1];
    float top = v00 * (1.f - wx) + v01 * wx;
    float bot = v10 * (1.f - wx) + v11 * wx;
    out[idx] = top * (1.f - wy) + bot * wy;
}

extern "C" void kernel_launch(void* const* d_in, const int* in_sizes, int n_in,
                              void* d_out, int out_size, void* d_ws, size_t ws_size,
                              hipStream_t stream) {
    const float* x      = (const float*)d_in[0];
    const float* conv_w = (const float*)d_in[1];
    const float* gamma  = (const float*)d_in[2];
    const float* beta   = (const float*)d_in[3];
    float* out = (float*)d_out;
    float* ws  = (float*)d_ws;

    // workspace (floats):
    //   sigma : [0, 18289152)
    //   coef  : [18289152, +1024)
    //   outlo : [18290176, +16257024)   -- ALIASED with xh/xl (prep+conv finish first)
    float* sigma = ws;
    float* coef  = ws + 18289152;
    float* outlo = ws + 18290176;
    u16* xhp = (u16*)(ws + 18290176);               // 16777216 u16 = 33.5 MB
    u16* xlp = xhp + (size_t)XTOT;                  // adjacent: xl = xh + XTOT
    u16* whT = xlp + (size_t)XTOT;                  // 663552 u16
    u16* wlT = whT + (size_t)WTOT;                  // adjacent: wl = wh + WTOT
    // total ws usage ~143 MB

    split_x_kernel<<<dim3(16, 128, 4), 256, 0, stream>>>(x, xhp, xlp);
    split_w_kernel<<<(9*CO*256)/256, 256, 0, stream>>>(conv_w, whT, wlT);

    conv_mfma_kernel<<<dim3(2, OH, N), 256, 0, stream>>>(xhp, whT, sigma);

    stats_kernel<<<CO, 1024, 0, stream>>>(sigma, gamma, beta, coef);

    fuse_kernel<<<(N * HW + 255) / 256, 256, 0, stream>>>(x, sigma, coef, outlo);

    upsample_kernel<<<(N * C * H * W) / 256, 256, 0, stream>>>(outlo, out);
}

// Round 4
// 695.071 us; speedup vs baseline: 2.0407x; 1.1281x over previous
//
#include <hip/hip_runtime.h>
#include <hip/hip_bf16.h>
#include <math.h>

#define N 4
#define C 256
#define H 128
#define W 128
#define CO 288        // GROUP * K * K = 32 * 9
#define OH 126
#define OW 126
#define GROUP 32
#define CPG 8
#define EPS 1e-5f

#define HW (OH*OW)          // 15876
#define XSLICE (H*W)        // 16384
#define XNSTRIDE (C*H*W)    // 4194304
#define SNSTRIDE (CO*HW)    // 4572288
#define LONSTRIDE (C*HW)    // 4064256
#define WSTRIDE (CO*256)    // 73728 u16 per shift s
#define WTOT (9*CO*256)     // 663552 u16 per table (wlT = whT + WTOT)
#define XTOT (N*H*W*C)      // 16777216 u16 per table (xl = xh + XTOT)

typedef unsigned short u16;
typedef __attribute__((ext_vector_type(8))) short short8;
typedef __attribute__((ext_vector_type(4))) float float4v;

__device__ inline u16 f2bf(float v) {
    __hip_bfloat16 b = __float2bfloat16(v);
    return __builtin_bit_cast(u16, b);
}
__device__ inline float bf2f(u16 u) {
    __hip_bfloat16 b = __builtin_bit_cast(__hip_bfloat16, u);
    return __bfloat162float(b);
}

// ---------------- Prep: split x into bf16 hi/lo, transpose to NHWC ----------------
// xh/xl layout: [n][h][w][ci] (ci contiguous); xl MUST be at xh + XTOT.
__global__ __launch_bounds__(256) void split_x_kernel(const float* __restrict__ x,
                                                      u16* __restrict__ xh,
                                                      u16* __restrict__ xl) {
    const int ci = threadIdx.x;          // 0..255
    const int w0 = blockIdx.x * 8;       // 16 groups
    const int h  = blockIdx.y;
    const int n  = blockIdx.z;
    const float* src = x + ((size_t)(n*C + ci)*H + h)*W + w0;
    float4 v0 = *(const float4*)src;
    float4 v1 = *(const float4*)(src + 4);
    float vals[8] = {v0.x, v0.y, v0.z, v0.w, v1.x, v1.y, v1.z, v1.w};
    size_t obase = ((size_t)(n*H + h)*W + w0)*C + ci;
    #pragma unroll
    for (int dw = 0; dw < 8; ++dw) {
        float v = vals[dw];
        u16 hb = f2bf(v);
        xh[obase + (size_t)dw*C] = hb;
        xl[obase + (size_t)dw*C] = f2bf(v - bf2f(hb));
    }
}

// ---------------- Prep: split w into bf16 hi/lo, layout [s][co][ci] ----------------
__global__ __launch_bounds__(256) void split_w_kernel(const float* __restrict__ wgt,
                                                      u16* __restrict__ whT,
                                                      u16* __restrict__ wlT) {
    const int i = blockIdx.x*256 + threadIdx.x;  // < 9*288*256 = 663552
    const int ci = i & 255;
    const int co = (i >> 8) % CO;
    const int s  = i / (CO*256);
    float v = wgt[(size_t)co*(C*9) + (size_t)ci*9 + s];
    u16 hb = f2bf(v);
    whT[i] = hb;
    wlT[i] = f2bf(v - bf2f(hb));
}

// ---------------- Conv 3x3 VALID via bf16 MFMA implicit GEMM ----------------
// Grid (2, 63, N), block 256 = 4 waves.
// Block: 2 output rows x 64 positions x 288 co.  Wave = 1 row x 64 pos x 144 co,
// acc[4 mt][9 j] float4 = 144 VGPR. 26 LDS reads feed 108 MFMAs per shift
// (0.24 reads/MFMA) -> MFMA-bound per the per-CU budget (4190 vs ~3460 cyc).
//
// Pipelined units as round 3: per shift s, {unit A: 72 MFMA (bh)} + {unit B: 36
// MFMA (bl)}; wsh double-buffered (one split per buffer); every unit issues the
// NEXT unit's global_load_lds before computing, so the vmcnt(0) drain at its
// ending __syncthreads covers loads that aged a full MFMA phase. xs restage
// overlaps into unit B of s=8 (readers finished at unit A's barrier).
__global__ __launch_bounds__(256, 2) void conv_mfma_kernel(const u16* __restrict__ xh,
                                                           const u16* __restrict__ whT,
                                                           float* __restrict__ sigma) {
    // xs chunk c = spq*264 + row*66 + col (spq = sp*4+q, row 0..3, col 0..65)
    __shared__ __align__(16) u16 xs[8*4*66*8];       // 33792 B
    // wsh: 2 buffers, each chunk c = q*288 + co (one split per buffer)
    __shared__ __align__(16) u16 wsh[2*4*288*8];     // 36864 B (total 70656 -> 2 blk/CU)

    const int tid  = threadIdx.x;
    const int wave = tid >> 6;
    const int lane = tid & 63;
    const int m16  = lane & 15;
    const int q    = lane >> 4;
    const int wr   = wave & 1;      // output row within block
    const int wc   = wave >> 1;     // co half (144 each)
    const int ow0  = blockIdx.x * 64;
    const int oh0  = blockIdx.y * 2;
    const int n    = blockIdx.z;

    // ---- w staging: 1152 chunks [q][co]; wave distribution 5/5/4/4 issues ----
    const int w_nw   = (wave < 2) ? 5 : 4;
    const int w_base = (wave < 2) ? wave*320 : 640 + (wave-2)*256;
    int wsrc[5];
    #pragma unroll
    for (int i = 0; i < 5; ++i) {
        int c = w_base + i*64 + lane;            // < 1152 by construction
        const int cq  = c / 288;
        const int cco = c - cq*288;
        wsrc[i] = cco*256 + cq*8;                // + split*WTOT + s*WSTRIDE + ci0
    }

    // ---- x staging: 2112 chunks; issue idx = 4t+wave, t<9, idx<33 ----
    int xoff[9];
    #pragma unroll
    for (int t = 0; t < 9; ++t) {
        int c = (4*t + wave)*64 + lane;
        if (c > 2111) c = 2111;                  // unused (guarded at issue)
        const int spq = c / 264;
        const int rem = c - spq*264;
        const int row = rem / 66;
        const int col = rem - row*66;
        int gc = ow0 + col; if (gc > W-1) gc = W-1;   // clamp feeds discarded outputs
        xoff[t] = (spq >> 2)*XTOT + ((n*H + oh0 + row)*W + gc)*C + (spq & 3)*8;
    }

    // ---- fragment read offsets (u16 units) ----
    const int aoff = (q*264 + wr*66 + m16)*8;    // + (ky*66+kx)*8 + mt*128 ; lo +8448
    const int boff = (q*288 + wc*144 + m16)*8;   // + buf*9216 + j*128

    float4v acc[4][9];
    #pragma unroll
    for (int mt = 0; mt < 4; ++mt)
        #pragma unroll
        for (int j = 0; j < 9; ++j) acc[mt][j] = (float4v)(0.f);

    // ---- prologue: stage xs(ci0=0) and w unit0 (s=0, hi) into buf 0 ----
    #pragma unroll
    for (int t = 0; t < 9; ++t)
        if (t < 8 || wave == 0)
            __builtin_amdgcn_global_load_lds((const uint*)(xh + xoff[t]),
                                             (uint*)(xs + (4*t + wave)*512), 16, 0, 0);
    #pragma unroll
    for (int i = 0; i < 5; ++i)
        if (i < w_nw)
            __builtin_amdgcn_global_load_lds((const uint*)(whT + wsrc[i]),
                                             (uint*)(wsh + (w_base + i*64)*8), 16, 0, 0);
    __syncthreads();

    int buf = 0;
    for (int ci0 = 0; ci0 < C; ci0 += 32) {
        #pragma unroll
        for (int ky = 0; ky < 3; ++ky)
        #pragma unroll
        for (int kx = 0; kx < 3; ++kx) {
            const int s = ky*3 + kx;

            // ======== unit A (bh): issue bl(s) into buf^1, compute 72 MFMA ========
            {
                const int soff = WTOT + s*WSTRIDE + ci0;     // lo split, same s
                #pragma unroll
                for (int i = 0; i < 5; ++i)
                    if (i < w_nw)
                        __builtin_amdgcn_global_load_lds(
                            (const uint*)(whT + soff + wsrc[i]),
                            (uint*)(wsh + ((buf^1)*1152 + w_base + i*64)*8), 16, 0, 0);
            }
            const int ab = aoff + (ky*66 + kx)*8;
            short8 ah0 = *(const short8*)&xs[ab];
            short8 ah1 = *(const short8*)&xs[ab + 128];
            short8 ah2 = *(const short8*)&xs[ab + 256];
            short8 ah3 = *(const short8*)&xs[ab + 384];
            {
                short8 al0 = *(const short8*)&xs[ab + 8448];
                short8 al1 = *(const short8*)&xs[ab + 8448 + 128];
                short8 al2 = *(const short8*)&xs[ab + 8448 + 256];
                short8 al3 = *(const short8*)&xs[ab + 8448 + 384];
                const u16* wb = wsh + buf*9216 + boff;
                __builtin_amdgcn_s_setprio(1);
                #pragma unroll
                for (int j = 0; j < 9; ++j) {
                    short8 bh = *(const short8*)&wb[j*128];
                    acc[0][j] = __builtin_amdgcn_mfma_f32_16x16x32_bf16(ah0, bh, acc[0][j], 0, 0, 0);
                    acc[1][j] = __builtin_amdgcn_mfma_f32_16x16x32_bf16(ah1, bh, acc[1][j], 0, 0, 0);
                    acc[2][j] = __builtin_amdgcn_mfma_f32_16x16x32_bf16(ah2, bh, acc[2][j], 0, 0, 0);
                    acc[3][j] = __builtin_amdgcn_mfma_f32_16x16x32_bf16(ah3, bh, acc[3][j], 0, 0, 0);
                    acc[0][j] = __builtin_amdgcn_mfma_f32_16x16x32_bf16(al0, bh, acc[0][j], 0, 0, 0);
                    acc[1][j] = __builtin_amdgcn_mfma_f32_16x16x32_bf16(al1, bh, acc[1][j], 0, 0, 0);
                    acc[2][j] = __builtin_amdgcn_mfma_f32_16x16x32_bf16(al2, bh, acc[2][j], 0, 0, 0);
                    acc[3][j] = __builtin_amdgcn_mfma_f32_16x16x32_bf16(al3, bh, acc[3][j], 0, 0, 0);
                }
                __builtin_amdgcn_s_setprio(0);
            }
            __syncthreads();     // drains bl(s) loads; bh buffer readers done
            buf ^= 1;

            // ======== unit B (bl): issue next hi into buf^1 (+xs restage at s=8) ====
            if (!(ci0 == C-32 && s == 8)) {
                int ns = s + 1, nci = ci0;
                if (ns == 9) { ns = 0; nci += 32; }
                const int soff = ns*WSTRIDE + nci;           // hi split of next unit
                #pragma unroll
                for (int i = 0; i < 5; ++i)
                    if (i < w_nw)
                        __builtin_amdgcn_global_load_lds(
                            (const uint*)(whT + soff + wsrc[i]),
                            (uint*)(wsh + ((buf^1)*1152 + w_base + i*64)*8), 16, 0, 0);
                if (s == 8) {    // xs readers finished at unit A's barrier
                    #pragma unroll
                    for (int t = 0; t < 9; ++t)
                        if (t < 8 || wave == 0)
                            __builtin_amdgcn_global_load_lds(
                                (const uint*)(xh + xoff[t] + nci),
                                (uint*)(xs + (4*t + wave)*512), 16, 0, 0);
                }
            }
            {
                const u16* wb = wsh + buf*9216 + boff;
                __builtin_amdgcn_s_setprio(1);
                #pragma unroll
                for (int j = 0; j < 9; ++j) {
                    short8 bl = *(const short8*)&wb[j*128];
                    acc[0][j] = __builtin_amdgcn_mfma_f32_16x16x32_bf16(ah0, bl, acc[0][j], 0, 0, 0);
                    acc[1][j] = __builtin_amdgcn_mfma_f32_16x16x32_bf16(ah1, bl, acc[1][j], 0, 0, 0);
                    acc[2][j] = __builtin_amdgcn_mfma_f32_16x16x32_bf16(ah2, bl, acc[2][j], 0, 0, 0);
                    acc[3][j] = __builtin_amdgcn_mfma_f32_16x16x32_bf16(ah3, bl, acc[3][j], 0, 0, 0);
                }
                __builtin_amdgcn_s_setprio(0);
            }
            __syncthreads();     // drains next-unit hi (+xs) loads; bl readers done
            buf ^= 1;
        }
    }

    // store: D[row=q*4+r][col=m16]; pos = mt*16+q*4+r, co = wc*144+j*16+m16
    #pragma unroll
    for (int mt = 0; mt < 4; ++mt) {
        const int posb = mt*16 + q*4;
        #pragma unroll
        for (int j = 0; j < 9; ++j) {
            const int co = wc*144 + j*16 + m16;
            float* dst = sigma + (size_t)n*SNSTRIDE + (size_t)co*HW + (oh0 + wr)*OW;
            #pragma unroll
            for (int r = 0; r < 4; ++r) {
                const int ow = ow0 + posb + r;
                if (ow < OW) dst[ow] = acc[mt][j][r];
            }
        }
    }
}

// ---------------- Per-channel mean/var over (N, OH, OW) ----------------
__global__ __launch_bounds__(1024) void stats_kernel(const float* __restrict__ sigma,
                                                     const float* __restrict__ gamma,
                                                     const float* __restrict__ beta,
                                                     float* __restrict__ coef) {
    const int c = blockIdx.x;
    float sum = 0.f, sq = 0.f;
    for (int n = 0; n < N; ++n) {
        const float* sp = sigma + (size_t)n*SNSTRIDE + (size_t)c*HW;
        for (int i = threadIdx.x; i < HW; i += 1024) {
            float v = sp[i];
            sum += v; sq += v * v;
        }
    }
    for (int off = 32; off > 0; off >>= 1) {
        sum += __shfl_down(sum, off, 64);
        sq  += __shfl_down(sq,  off, 64);
    }
    __shared__ float ls[16], lq[16];
    const int wid = threadIdx.x >> 6, lane = threadIdx.x & 63;
    if (lane == 0) { ls[wid] = sum; lq[wid] = sq; }
    __syncthreads();
    if (threadIdx.x == 0) {
        float S = 0.f, Q = 0.f;
        #pragma unroll
        for (int i = 0; i < 16; ++i) { S += ls[i]; Q += lq[i]; }
        const float cnt = (float)(N * HW);
        float mean = S / cnt;
        float var  = Q / cnt - mean * mean;
        float a = gamma[c] * rsqrtf(var + EPS);
        coef[c]      = a;
        coef[CO + c] = beta[c] - mean * a;
    }
}

// ---------------- Fused normalize + softmax(288) + grouped dynamic 3x3 ----------------
__global__ __launch_bounds__(256) void fuse_kernel(const float* __restrict__ x,
                                                   const float* __restrict__ sigma,
                                                   const float* __restrict__ coef,
                                                   float* __restrict__ outlo) {
    __shared__ float a[CO], b[CO];
    for (int i = threadIdx.x; i < CO; i += 256) {
        a[i] = coef[i];
        b[i] = coef[CO + i];
    }
    __syncthreads();

    const int gpos = blockIdx.x * 256 + threadIdx.x;
    if (gpos >= N * HW) return;
    const int n  = gpos / HW;
    const int hw = gpos - n * HW;
    const int oh = hw / OW;
    const int ow = hw - oh * OW;

    const float* sp = sigma + (size_t)n * SNSTRIDE + hw;

    float mx = -1e30f;
    for (int ch = 0; ch < CO; ++ch) {
        float s = sp[(size_t)ch * HW] * a[ch] + b[ch];
        mx = fmaxf(mx, s);
    }
    float sum = 0.f;
    for (int ch = 0; ch < CO; ++ch) {
        float s = sp[(size_t)ch * HW] * a[ch] + b[ch];
        sum += __expf(s - mx);
    }
    const float inv = 1.f / sum;

    const float* xb = x + (size_t)n * XNSTRIDE + oh * W + ow;
    float* ob = outlo + (size_t)n * LONSTRIDE + hw;

    for (int g = 0; g < GROUP; ++g) {
        float acc[CPG];
        #pragma unroll
        for (int c = 0; c < CPG; ++c) acc[c] = 0.f;
        #pragma unroll
        for (int p = 0; p < 9; ++p) {
            const int ch = g * 9 + p;
            float s = sp[(size_t)ch * HW] * a[ch] + b[ch];
            float wv = __expf(s - mx) * inv;
            const float* xr = xb + (size_t)(g * CPG) * XSLICE + (p / 3) * W + (p % 3);
            #pragma unroll
            for (int c = 0; c < CPG; ++c)
                acc[c] += xr[(size_t)c * XSLICE] * wv;
        }
        #pragma unroll
        for (int c = 0; c < CPG; ++c)
            ob[(size_t)(g * CPG + c) * HW] = acc[c];
    }
}

// ---------------- Bilinear align-corners upsample 126 -> 128 ----------------
__global__ __launch_bounds__(256) void upsample_kernel(const float* __restrict__ lo,
                                                       float* __restrict__ out) {
    const int idx = blockIdx.x * 256 + threadIdx.x;
    const int xi = idx & (W - 1);
    const int yi = (idx >> 7) & (H - 1);
    const int nc = idx >> 14;

    const float scale = 125.0f / 127.0f;
    const float sy = yi * scale;
    const float sx = xi * scale;
    int y0 = (int)sy;
    int x0 = (int)sx;
    float wy = sy - (float)y0;
    float wx = sx - (float)x0;
    int y1 = min(y0 + 1, OH - 1);
    int x1 = min(x0 + 1, OW - 1);

    const float* p = lo + (size_t)nc * HW;
    float v00 = p[y0 * OW + x0], v01 = p[y0 * OW + x1];
    float v10 = p[y1 * OW + x0], v11 = p[y1 * OW + x1];
    float top = v00 * (1.f - wx) + v01 * wx;
    float bot = v10 * (1.f - wx) + v11 * wx;
    out[idx] = top * (1.f - wy) + bot * wy;
}

extern "C" void kernel_launch(void* const* d_in, const int* in_sizes, int n_in,
                              void* d_out, int out_size, void* d_ws, size_t ws_size,
                              hipStream_t stream) {
    const float* x      = (const float*)d_in[0];
    const float* conv_w = (const float*)d_in[1];
    const float* gamma  = (const float*)d_in[2];
    const float* beta   = (const float*)d_in[3];
    float* out = (float*)d_out;
    float* ws  = (float*)d_ws;

    // workspace (floats):
    //   sigma : [0, 18289152)
    //   coef  : [18289152, +1024)
    //   outlo : [18290176, +16257024)   -- ALIASED with xh/xl (prep+conv finish first)
    float* sigma = ws;
    float* coef  = ws + 18289152;
    float* outlo = ws + 18290176;
    u16* xhp = (u16*)(ws + 18290176);               // 16777216 u16 = 33.5 MB
    u16* xlp = xhp + (size_t)XTOT;                  // adjacent: xl = xh + XTOT
    u16* whT = xlp + (size_t)XTOT;                  // 663552 u16
    u16* wlT = whT + (size_t)WTOT;                  // adjacent: wl = wh + WTOT
    // total ws usage ~143 MB

    split_x_kernel<<<dim3(16, 128, 4), 256, 0, stream>>>(x, xhp, xlp);
    split_w_kernel<<<(9*CO*256)/256, 256, 0, stream>>>(conv_w, whT, wlT);

    conv_mfma_kernel<<<dim3(2, 63, N), 256, 0, stream>>>(xhp, whT, sigma);

    stats_kernel<<<CO, 1024, 0, stream>>>(sigma, gamma, beta, coef);

    fuse_kernel<<<(N * HW + 255) / 256, 256, 0, stream>>>(x, sigma, coef, outlo);

    upsample_kernel<<<(N * C * H * W) / 256, 256, 0, stream>>>(outlo, out);
}